// Round 3
// baseline (166019.458 us; speedup 1.0000x reference)
//
#include <hip/hip_runtime.h>
#include <hip/hip_bf16.h>

typedef __attribute__((ext_vector_type(8))) __bf16 bf16x8;
typedef __attribute__((ext_vector_type(4))) float f32x4;

constexpr int B_N = 64;
constexpr int T_N = 1024;
constexpr long long BT_N = (long long)B_N * T_N;   // 65536

// ---------------------------------------------------------------------------
// fp32 -> bf16 convert (4 elems/thread, grid-stride)
// ---------------------------------------------------------------------------
__global__ void cvt_f32_bf16(const float* __restrict__ src,
                             __hip_bfloat16* __restrict__ dst, long long n4)
{
    long long i = (long long)blockIdx.x * blockDim.x + threadIdx.x;
    long long stride = (long long)gridDim.x * blockDim.x;
    for (; i < n4; i += stride) {
        float4 v = ((const float4*)src)[i];
        __hip_bfloat16* d = dst + i * 4;
        d[0] = __float2bfloat16(v.x);
        d[1] = __float2bfloat16(v.y);
        d[2] = __float2bfloat16(v.z);
        d[3] = __float2bfloat16(v.w);
    }
}

// ---------------------------------------------------------------------------
// Permute W_hh (4 layers, [1536][512] fp32) into fragment-linear bf16:
// dst[l][((tl*16 + kc)*64 + lane)*8 + jj] = W[l][tl*16 + (lane&15)][kc*32 + (lane>>4)*8 + jj]
// so the scan's B-fragment loads are contiguous 16 B/lane streams.
// ---------------------------------------------------------------------------
__global__ void permute_whh(const float* __restrict__ src,
                            __hip_bfloat16* __restrict__ dst)
{
    int gidx = blockIdx.x * blockDim.x + threadIdx.x;   // one 8-elem group each
    const int PER_L = 96 * 16 * 64;                     // 98304 groups/layer
    if (gidx >= 4 * PER_L) return;
    int l   = gidx / PER_L;
    int r   = gidx - l * PER_L;
    int tl  = r >> 10;           // /1024
    int rem = r & 1023;
    int kc   = rem >> 6;
    int lane = rem & 63;
    int n  = tl * 16 + (lane & 15);
    int k0 = kc * 32 + (lane >> 4) * 8;
    const float* sp = src + ((size_t)l * 1536 + n) * 512 + k0;
    float4 a = *(const float4*)sp;
    float4 b = *(const float4*)(sp + 4);
    __hip_bfloat16* dp = dst + (size_t)gidx * 8;
    dp[0] = __float2bfloat16(a.x); dp[1] = __float2bfloat16(a.y);
    dp[2] = __float2bfloat16(a.z); dp[3] = __float2bfloat16(a.w);
    dp[4] = __float2bfloat16(b.x); dp[5] = __float2bfloat16(b.y);
    dp[6] = __float2bfloat16(b.z); dp[7] = __float2bfloat16(b.w);
}

// ---------------------------------------------------------------------------
// bf16 MFMA GEMM: C[M,N] = act(A[M,K] @ W[N,K]^T + bias)  (unchanged r2)
// ---------------------------------------------------------------------------
__device__ inline void store_val(float* p, float v) { *p = v; }
__device__ inline void store_val(__hip_bfloat16* p, float v) { *p = __float2bfloat16(v); }

template <typename OutT, bool RELU>
__global__ __launch_bounds__(256)
void mfma_gemm(const __hip_bfloat16* __restrict__ A,
               const __hip_bfloat16* __restrict__ W,
               const float* __restrict__ bias,
               OutT* __restrict__ C, int M, int N, int K)
{
    constexpr int LDT = 72;
    __shared__ __hip_bfloat16 Asl[128 * LDT];
    __shared__ __hip_bfloat16 Bsl[128 * LDT];

    const int tid  = threadIdx.x;
    const int wv   = tid >> 6;
    const int lane = tid & 63;
    const int quad = lane >> 4;
    const int l16  = lane & 15;
    const int bm = blockIdx.y, bn = blockIdx.x;
    const int m0w = (wv & 1) * 64;
    const int n0w = (wv >> 1) * 64;

    f32x4 acc[4][4] = {};

    for (int k0 = 0; k0 < K; k0 += 64) {
        __syncthreads();
#pragma unroll
        for (int i = 0; i < 4; ++i) {
            int c = tid + i * 256;
            int row = c >> 3, ch = c & 7;
            bf16x8 va = *(const bf16x8*)(A + (size_t)(bm * 128 + row) * K + k0 + ch * 8);
            bf16x8 vb = *(const bf16x8*)(W + (size_t)(bn * 128 + row) * K + k0 + ch * 8);
            *(bf16x8*)(Asl + row * LDT + ch * 8) = va;
            *(bf16x8*)(Bsl + row * LDT + ch * 8) = vb;
        }
        __syncthreads();
#pragma unroll
        for (int kc = 0; kc < 2; ++kc) {
            const int koff = kc * 32 + quad * 8;
            bf16x8 af[4], bfr[4];
#pragma unroll
            for (int mt = 0; mt < 4; ++mt)
                af[mt] = *(const bf16x8*)(Asl + (m0w + mt * 16 + l16) * LDT + koff);
#pragma unroll
            for (int nt = 0; nt < 4; ++nt)
                bfr[nt] = *(const bf16x8*)(Bsl + (n0w + nt * 16 + l16) * LDT + koff);
#pragma unroll
            for (int mt = 0; mt < 4; ++mt)
#pragma unroll
                for (int nt = 0; nt < 4; ++nt)
                    acc[mt][nt] = __builtin_amdgcn_mfma_f32_16x16x32_bf16(
                        af[mt], bfr[nt], acc[mt][nt], 0, 0, 0);
        }
    }

#pragma unroll
    for (int nt = 0; nt < 4; ++nt) {
        const int col = bn * 128 + n0w + nt * 16 + l16;
        const float bv = bias[col];
#pragma unroll
        for (int mt = 0; mt < 4; ++mt) {
#pragma unroll
            for (int rg = 0; rg < 4; ++rg) {
                const int row = bm * 128 + m0w + mt * 16 + quad * 4 + rg;
                float v = acc[mt][nt][rg] + bv;
                if (RELU) v = fmaxf(v, 0.f);
                store_val(C + (size_t)row * N + col, v);
            }
        }
    }
}

// ---------------------------------------------------------------------------
// Batch-parallel GRU scan: NO cross-block communication.
// Grid: 4 blocks x 512 threads (8 waves, 1 block/CU). Block g owns batch
// rows b = g*16 .. g*16+15. h kept in LDS (double-buffered, stride 524 —
// bank-conflict-free writes). W_hh streamed from L2 in fragment-linear
// layout. Wave w owns j in [64w, 64w+64) for ALL THREE gates -> in-register
// gate combine. One __syncthreads per step.
// ---------------------------------------------------------------------------
__global__ __launch_bounds__(512, 2)
void gru_scan_batch(const __hip_bfloat16* __restrict__ gi,   // [64][1024][1536]
                    const __hip_bfloat16* __restrict__ whp,  // fragment-linear
                    const float* __restrict__ bhh,           // [1536]
                    __hip_bfloat16* __restrict__ y)          // [64][1024][512]
{
    constexpr int HP = 524;                 // padded LDS h stride
    __shared__ __hip_bfloat16 hbuf[2][16][HP];

    const int tid  = threadIdx.x;
    const int w    = tid >> 6;
    const int lane = tid & 63;
    const int quad = lane >> 4;
    const int l16  = lane & 15;
    const int g    = blockIdx.x;
    const int m0   = quad * 4;              // combine rows m = m0 + rg

    // h(-1) = 0
    for (int i = tid; i < 2 * 16 * HP; i += 512)
        ((__hip_bfloat16*)hbuf)[i] = __float2bfloat16(0.f);

    float br[4], bz[4], bn_[4];
#pragma unroll
    for (int s = 0; s < 4; ++s) {
        const int j = w * 64 + s * 16 + l16;
        br[s]  = bhh[j];
        bz[s]  = bhh[512 + j];
        bn_[s] = bhh[1024 + j];
    }
    __syncthreads();

    for (int t = 0; t < 1024; ++t) {
        const int cur = t & 1, nxt = cur ^ 1;

        // gi operands for the combine: issued first, consumed ~6500 cyc later
        __hip_bfloat16 pgi[3][4][4];
#pragma unroll
        for (int rg = 0; rg < 4; ++rg) {
            const __hip_bfloat16* gp =
                gi + ((size_t)(g * 16 + m0 + rg) * 1024 + t) * 1536 + w * 64 + l16;
#pragma unroll
            for (int s = 0; s < 4; ++s) {
                pgi[0][rg][s] = gp[s * 16];
                pgi[1][rg][s] = gp[512 + s * 16];
                pgi[2][rg][s] = gp[1024 + s * 16];
            }
        }

        // gh = h_{t-1} @ W_hh^T for this block's 16 rows, wave's 12 n-tiles
        f32x4 acc[3][4] = {};
        bf16x8 afc = *(const bf16x8*)&hbuf[cur][l16][quad * 8];
#pragma unroll
        for (int kc = 0; kc < 16; ++kc) {
            bf16x8 afn;
            if (kc < 15)
                afn = *(const bf16x8*)&hbuf[cur][l16][(kc + 1) * 32 + quad * 8];
            const __hip_bfloat16* wp = whp + ((size_t)kc * 64 + lane) * 8;
#pragma unroll
            for (int gate = 0; gate < 3; ++gate)
#pragma unroll
                for (int s = 0; s < 4; ++s) {
                    const int tl = gate * 32 + w * 4 + s;
                    bf16x8 bf = *(const bf16x8*)(wp + (size_t)tl * (16 * 64 * 8));
                    acc[gate][s] = __builtin_amdgcn_mfma_f32_16x16x32_bf16(
                        afc, bf, acc[gate][s], 0, 0, 0);
                }
            afc = afn;
        }

        // in-register gate combine; write h_t to LDS(next) + y(global)
#pragma unroll
        for (int s = 0; s < 4; ++s) {
            const int j = w * 64 + s * 16 + l16;
#pragma unroll
            for (int rg = 0; rg < 4; ++rg) {
                const int m = m0 + rg;
                float hprev = __bfloat162float(hbuf[cur][m][j]);
                float r = 1.f / (1.f + __expf(-(__bfloat162float(pgi[0][rg][s]) + acc[0][s][rg] + br[s])));
                float z = 1.f / (1.f + __expf(-(__bfloat162float(pgi[1][rg][s]) + acc[1][s][rg] + bz[s])));
                float n = tanhf(__bfloat162float(pgi[2][rg][s]) + r * (acc[2][s][rg] + bn_[s]));
                float hv = (1.f - z) * n + z * hprev;
                __hip_bfloat16 hb = __float2bfloat16(hv);
                hbuf[nxt][m][j] = hb;
                y[((size_t)(g * 16 + m) * 1024 + t) * 512 + j] = hb;
            }
        }
        __syncthreads();
    }
}

// ---------------------------------------------------------------------------
// Host-side launch
// ---------------------------------------------------------------------------
extern "C" void kernel_launch(void* const* d_in, const int* in_sizes, int n_in,
                              void* d_out, int out_size, void* d_ws, size_t ws_size,
                              hipStream_t stream)
{
    const float* x    = (const float*)d_in[0];
    const float* w_in = (const float*)d_in[1];
    const float* b_in = (const float*)d_in[2];
    const float* w_ih = (const float*)d_in[3];
    const float* w_hh = (const float*)d_in[4];
    const float* b_ih = (const float*)d_in[5];
    const float* b_hh = (const float*)d_in[6];
    const float* w_o1 = (const float*)d_in[7];
    const float* b_o1 = (const float*)d_in[8];
    const float* w_o2 = (const float*)d_in[9];
    const float* b_o2 = (const float*)d_in[10];
    float* out = (float*)d_out;

    // workspace layout (~283 MB)
    char* ws = (char*)d_ws;
    const size_t GI_BYTES  = (size_t)BT_N * 1536 * 2;  // 201,326,592
    const size_t ACT_BYTES = (size_t)BT_N * 512 * 2;   //  67,108,864
    __hip_bfloat16* gi  = (__hip_bfloat16*)ws;
    __hip_bfloat16* act = (__hip_bfloat16*)(ws + GI_BYTES);
    __hip_bfloat16* wbf = (__hip_bfloat16*)(ws + GI_BYTES + ACT_BYTES);
    __hip_bfloat16* xbf = gi;     // alias: dead before gi written
    __hip_bfloat16* tmp = gi;     // alias: MLP intermediate

    __hip_bfloat16* w_in_bf = wbf;                     // 262144
    __hip_bfloat16* w_ih_bf = wbf + 262144;            // 3,145,728
    __hip_bfloat16* whp     = w_ih_bf + 3145728;       // 3,145,728 (permuted W_hh)
    __hip_bfloat16* w_o1_bf = whp + 3145728;           // 262144
    __hip_bfloat16* w_o2_bf = w_o1_bf + 262144;        // 262144

    cvt_f32_bf16<<<256, 256, 0, stream>>>(w_in, w_in_bf, 262144 / 4);
    cvt_f32_bf16<<<1024, 256, 0, stream>>>(w_ih, w_ih_bf, 3145728 / 4);
    permute_whh<<<1536, 256, 0, stream>>>(w_hh, whp);
    cvt_f32_bf16<<<256, 256, 0, stream>>>(w_o1, w_o1_bf, 262144 / 4);
    cvt_f32_bf16<<<256, 256, 0, stream>>>(w_o2, w_o2_bf, 262144 / 4);
    cvt_f32_bf16<<<4096, 256, 0, stream>>>(x, xbf, BT_N * 512 / 4);

    const int M = (int)BT_N;

    // input linear + ReLU -> act (bf16)
    mfma_gemm<__hip_bfloat16, true><<<dim3(4, 512), 256, 0, stream>>>(
        xbf, w_in_bf, b_in, act, M, 512, 512);

    for (int l = 0; l < 4; ++l) {
        const __hip_bfloat16* wih_l = w_ih_bf + (size_t)l * 1536 * 512;
        const __hip_bfloat16* whp_l = whp + (size_t)l * 1536 * 512;
        const float* bih_l = b_ih + (size_t)l * 1536;
        const float* bhh_l = b_hh + (size_t)l * 1536;

        // gi = act @ w_ih^T + b_ih  (bf16)
        mfma_gemm<__hip_bfloat16, false><<<dim3(12, 512), 256, 0, stream>>>(
            act, wih_l, bih_l, gi, M, 1536, 512);

        // batch-parallel scan; overwrites act with this layer's output
        gru_scan_batch<<<dim3(4), dim3(512), 0, stream>>>(gi, whp_l, bhh_l, act);
    }

    // output MLP: act -> tmp (relu, bf16) -> out (fp32)
    mfma_gemm<__hip_bfloat16, true><<<dim3(4, 512), 256, 0, stream>>>(
        act, w_o1_bf, b_o1, tmp, M, 512, 512);
    mfma_gemm<float, false><<<dim3(4, 512), 256, 0, stream>>>(
        tmp, w_o2_bf, b_o2, out, M, 512, 512);
}